// Round 1
// baseline (529.476 us; speedup 1.0000x reference)
//
#include <hip/hip_runtime.h>
#include <math.h>

#define BB 16
#define TQ 512
#define TK 1024
#define DD 512

// Tiled fp32 GEMM.
//  BT=true : C[m][n] = sum_k A[m][k] * Bm[n][k]   (B row-major N x K, "NT")
//  BT=false: C[m][n] = sum_k A[m][k] * Bm[k][n]   (B row-major K x N, "NN")
// Optional bias add (per-n) and scalar scale (from device pointer).
// Fixed tile: BM=BN=64, BK=16, 256 threads, 4x4 acc per thread.
// All dims must be multiples of the tile (true here: 512/1024/8192).
template <bool BT, bool BIAS, bool SCALE>
__global__ __launch_bounds__(256) void gemm_kernel(
    const float* __restrict__ A, const float* __restrict__ Bm,
    float* __restrict__ C, const float* __restrict__ bias,
    const float* __restrict__ scl,
    int M, int N, int K, long sA, long sB, long sC)
{
    __shared__ float As[16][64 + 1];
    __shared__ float Bs[16][64 + 1];

    const int bz = blockIdx.z;
    A  += (long)bz * sA;
    Bm += (long)bz * sB;
    C  += (long)bz * sC;

    const int m0 = blockIdx.y * 64;
    const int n0 = blockIdx.x * 64;
    const int tid = threadIdx.x;          // 0..255
    const int tx = tid & 15;              // 0..15 -> n
    const int ty = tid >> 4;              // 0..15 -> m

    float acc[4][4] = {};

    for (int k0 = 0; k0 < K; k0 += 16) {
        // ---- load A tile: 64 rows x 16 k, one float4 per thread, coalesced in K
        {
            const int r  = tid >> 2;          // 0..63
            const int c4 = (tid & 3) << 2;    // 0,4,8,12
            const float4 v = *(const float4*)(A + (long)(m0 + r) * K + k0 + c4);
            As[c4 + 0][r] = v.x; As[c4 + 1][r] = v.y;
            As[c4 + 2][r] = v.z; As[c4 + 3][r] = v.w;
        }
        if (BT) {
            const int r  = tid >> 2;          // 0..63 -> n
            const int c4 = (tid & 3) << 2;    // k
            const float4 v = *(const float4*)(Bm + (long)(n0 + r) * K + k0 + c4);
            Bs[c4 + 0][r] = v.x; Bs[c4 + 1][r] = v.y;
            Bs[c4 + 2][r] = v.z; Bs[c4 + 3][r] = v.w;
        } else {
            const int r  = tid >> 4;          // 0..15 -> k
            const int c4 = (tid & 15) << 2;   // 0..60 -> n
            const float4 v = *(const float4*)(Bm + (long)(k0 + r) * N + n0 + c4);
            Bs[r][c4 + 0] = v.x; Bs[r][c4 + 1] = v.y;
            Bs[r][c4 + 2] = v.z; Bs[r][c4 + 3] = v.w;
        }
        __syncthreads();

        #pragma unroll
        for (int k = 0; k < 16; ++k) {
            float a[4], b[4];
            #pragma unroll
            for (int i = 0; i < 4; ++i) a[i] = As[k][ty * 4 + i];
            #pragma unroll
            for (int j = 0; j < 4; ++j) b[j] = Bs[k][tx * 4 + j];
            #pragma unroll
            for (int i = 0; i < 4; ++i)
                #pragma unroll
                for (int j = 0; j < 4; ++j)
                    acc[i][j] += a[i] * b[j];
        }
        __syncthreads();
    }

    const float s = SCALE ? scl[0] : 1.0f;
    #pragma unroll
    for (int i = 0; i < 4; ++i) {
        const int m = m0 + ty * 4 + i;
        #pragma unroll
        for (int j = 0; j < 4; ++j) {
            const int n = n0 + tx * 4 + j;
            float v = acc[i][j];
            if (BIAS)  v += bias[n];
            if (SCALE) v *= s;
            C[(long)m * N + n] = v;
        }
    }
}

// One block (256 threads) per (b,q) row of 1024 scores.
// Softmax over k < len; masked positions written as 0 (softmax(-inf)=0).
__global__ __launch_bounds__(256) void softmax_kernel(
    float* __restrict__ attn, const int* __restrict__ lens)
{
    const int row = blockIdx.x;          // b*TQ + q
    const int b   = row / TQ;
    const int len = lens[b];             // in [512, 1024]
    float* p = attn + (long)row * TK;

    const int tid  = threadIdx.x;
    const int lane = tid & 63;
    const int wave = tid >> 6;

    float x[4];
    float mx = -INFINITY;
    #pragma unroll
    for (int i = 0; i < 4; ++i) {
        const int k = tid + i * 256;
        x[i] = (k < len) ? p[k] : -INFINITY;
        mx = fmaxf(mx, x[i]);
    }
    #pragma unroll
    for (int off = 32; off; off >>= 1) mx = fmaxf(mx, __shfl_xor(mx, off, 64));

    __shared__ float red[8];
    if (lane == 0) red[wave] = mx;
    __syncthreads();
    mx = fmaxf(fmaxf(red[0], red[1]), fmaxf(red[2], red[3]));

    float e[4];
    float sum = 0.0f;
    #pragma unroll
    for (int i = 0; i < 4; ++i) {
        const int k = tid + i * 256;
        e[i] = (k < len) ? __expf(x[i] - mx) : 0.0f;
        sum += e[i];
    }
    #pragma unroll
    for (int off = 32; off; off >>= 1) sum += __shfl_xor(sum, off, 64);
    if (lane == 0) red[4 + wave] = sum;
    __syncthreads();
    sum = red[4] + red[5] + red[6] + red[7];

    const float inv = 1.0f / sum;
    #pragma unroll
    for (int i = 0; i < 4; ++i) {
        const int k = tid + i * 256;
        p[k] = e[i] * inv;               // masked lanes write exact 0
    }
}

extern "C" void kernel_launch(void* const* d_in, const int* in_sizes, int n_in,
                              void* d_out, int out_size, void* d_ws, size_t ws_size,
                              hipStream_t stream) {
    (void)in_sizes; (void)n_in; (void)out_size; (void)d_ws; (void)ws_size;

    const float* query = (const float*)d_in[0];   // B,TQ,D
    const float* keys  = (const float*)d_in[1];   // B,TK,D
    const int*   lens  = (const int*)d_in[2];     // B
    const float* Wq    = (const float*)d_in[3];   // D,D  (row d, col e)
    const float* bq    = (const float*)d_in[4];   // D
    const float* scale = (const float*)d_in[5];   // 1

    float* out  = (float*)d_out;
    float* ctx  = out;                               // B*TQ*D
    float* attn = out + (size_t)BB * TQ * DD;        // B*TQ*TK
    // att_query scratch lives in the context output region (same size,
    // dead before the context GEMM writes it).
    float* aq = ctx;

    // 1) att_query = query @ Wq^T + bq        (NT, single "batch", M=8192)
    gemm_kernel<true, true, false><<<dim3(DD / 64, (BB * TQ) / 64, 1), 256, 0, stream>>>(
        query, Wq, aq, bq, nullptr, BB * TQ, DD, DD, 0, 0, 0);

    // 2) scores = att_query @ keys^T * scale  (NT, batched over B) -> attn region
    gemm_kernel<true, false, true><<<dim3(TK / 64, TQ / 64, BB), 256, 0, stream>>>(
        aq, keys, attn, nullptr, scale, TQ, TK, DD,
        (long)TQ * DD, (long)TK * DD, (long)TQ * TK);

    // 3) masked softmax in place over attn rows
    softmax_kernel<<<BB * TQ, 256, 0, stream>>>(attn, lens);

    // 4) context = attn @ keys                (NN, batched) -> overwrites aq (dead)
    gemm_kernel<false, false, false><<<dim3(DD / 64, TQ / 64, BB), 256, 0, stream>>>(
        attn, keys, ctx, nullptr, nullptr, TQ, DD, TK,
        (long)TQ * TK, (long)TK * DD, (long)TQ * DD);
}

// Round 2
// 225.170 us; speedup vs baseline: 2.3514x; 2.3514x over previous
//
#include <hip/hip_runtime.h>
#include <math.h>

#define BB 16
#define TQ 512
#define TK 1024
#define DD 512

typedef __bf16 bf16x8 __attribute__((ext_vector_type(8)));
typedef float f32x4 __attribute__((ext_vector_type(4)));

__device__ __forceinline__ unsigned short f2bf_rne(float x) {
    unsigned int u = __float_as_uint(x);
    u += 0x7fffu + ((u >> 16) & 1u);
    return (unsigned short)(u >> 16);
}
__device__ __forceinline__ float bf2f(unsigned short h) {
    return __uint_as_float(((unsigned int)h) << 16);
}

// MFMA GEMM, fp32 in / fp32 out, bf16 (or split-bf16) compute.
//  BT=true : C[m][n] = sum_k A[m][k] * Bm[n][k]   (B row-major N x K)
//  BT=false: C[m][n] = sum_k A[m][k] * Bm[k][n]   (B row-major K x N)
// SPLIT: A,B represented as hi+lo bf16; acc += Ah*Bh + Ah*Bl + Al*Bh (~fp32 acc).
// Block tile 128x128, 256 threads (4 waves, 2x2), K-step 32.
// Requires M%128==0, N%128==0, K%32==0.
template<bool BT, bool SPLIT, bool BIAS, bool SCALE>
__global__ __launch_bounds__(256) void mfma_gemm(
    const float* __restrict__ A, const float* __restrict__ Bm,
    float* __restrict__ C, const float* __restrict__ bias,
    const float* __restrict__ scl,
    int M, int N, int K, long sA, long sB, long sC)
{
    (void)M;
    constexpr int LDT = 40;  // ushorts per 32-k row: 32 + 8 pad (keeps 16B align, 2-way banks)
    __shared__ unsigned short As_hi[128 * LDT];
    __shared__ unsigned short Bs_hi[128 * LDT];
    __shared__ unsigned short As_lo[SPLIT ? 128 * LDT : 8];
    __shared__ unsigned short Bs_lo[SPLIT ? 128 * LDT : 8];

    const int bz = blockIdx.z;
    A  += (long)bz * sA;
    Bm += (long)bz * sB;
    C  += (long)bz * sC;

    const int m0 = blockIdx.y * 128;
    const int n0 = blockIdx.x * 128;
    const int tid  = threadIdx.x;
    const int lane = tid & 63;
    const int wave = tid >> 6;
    const int wm0 = (wave >> 1) * 64;   // wave's m offset in block tile
    const int wn0 = (wave & 1) * 64;    // wave's n offset
    const int fm = lane & 15;           // fragment row/col index
    const int fq = lane >> 4;           // quad 0..3

    f32x4 acc[4][4];
    #pragma unroll
    for (int i = 0; i < 4; ++i)
        #pragma unroll
        for (int j = 0; j < 4; ++j) {
            f32x4 z = {0.f, 0.f, 0.f, 0.f};
            acc[i][j] = z;
        }

    for (int k0 = 0; k0 < K; k0 += 32) {
        // ---- stage A tile: 128 rows x 32 k (fp32 -> bf16 hi/lo)
        #pragma unroll
        for (int i = 0; i < 4; ++i) {
            const int s   = tid + i * 256;       // 0..1023 float4 slots
            const int row = s >> 3;              // 0..127
            const int c4  = (s & 7) << 2;        // 0,4,...,28
            const float4 v = *(const float4*)(A + (long)(m0 + row) * K + k0 + c4);
            const unsigned short h0 = f2bf_rne(v.x), h1 = f2bf_rne(v.y),
                                 h2 = f2bf_rne(v.z), h3 = f2bf_rne(v.w);
            *(ushort4*)&As_hi[row * LDT + c4] = make_ushort4(h0, h1, h2, h3);
            if (SPLIT) {
                const unsigned short l0 = f2bf_rne(v.x - bf2f(h0)),
                                     l1 = f2bf_rne(v.y - bf2f(h1)),
                                     l2 = f2bf_rne(v.z - bf2f(h2)),
                                     l3 = f2bf_rne(v.w - bf2f(h3));
                *(ushort4*)&As_lo[row * LDT + c4] = make_ushort4(l0, l1, l2, l3);
            }
        }
        // ---- stage B tile into Bs[n][k]
        if (BT) {
            #pragma unroll
            for (int i = 0; i < 4; ++i) {
                const int s   = tid + i * 256;
                const int row = s >> 3;          // n
                const int c4  = (s & 7) << 2;    // k
                const float4 v = *(const float4*)(Bm + (long)(n0 + row) * K + k0 + c4);
                const unsigned short h0 = f2bf_rne(v.x), h1 = f2bf_rne(v.y),
                                     h2 = f2bf_rne(v.z), h3 = f2bf_rne(v.w);
                *(ushort4*)&Bs_hi[row * LDT + c4] = make_ushort4(h0, h1, h2, h3);
                if (SPLIT) {
                    const unsigned short l0 = f2bf_rne(v.x - bf2f(h0)),
                                         l1 = f2bf_rne(v.y - bf2f(h1)),
                                         l2 = f2bf_rne(v.z - bf2f(h2)),
                                         l3 = f2bf_rne(v.w - bf2f(h3));
                    *(ushort4*)&Bs_lo[row * LDT + c4] = make_ushort4(l0, l1, l2, l3);
                }
            }
        } else {
            // B is K x N: thread t covers n = t&127, k-half = t>>7 (16 k each).
            const int n  = tid & 127;
            const int kh = tid >> 7;
            const float* src = Bm + (long)(k0 + kh * 16) * N + n0 + n;
            unsigned short hb[16], lb[16];
            #pragma unroll
            for (int j2 = 0; j2 < 16; ++j2) {
                const float x = src[(long)j2 * N];
                hb[j2] = f2bf_rne(x);
                if (SPLIT) lb[j2] = f2bf_rne(x - bf2f(hb[j2]));
            }
            #pragma unroll
            for (int w2 = 0; w2 < 4; ++w2) {
                *(ushort4*)&Bs_hi[n * LDT + kh * 16 + w2 * 4] =
                    make_ushort4(hb[w2*4], hb[w2*4+1], hb[w2*4+2], hb[w2*4+3]);
                if (SPLIT)
                    *(ushort4*)&Bs_lo[n * LDT + kh * 16 + w2 * 4] =
                        make_ushort4(lb[w2*4], lb[w2*4+1], lb[w2*4+2], lb[w2*4+3]);
            }
        }
        __syncthreads();

        // ---- fragments + MFMA
        bf16x8 ah[4], bh[4], al[4], bl[4];
        #pragma unroll
        for (int i = 0; i < 4; ++i) {
            const int ra = (wm0 + 16 * i + fm) * LDT + fq * 8;
            ah[i] = *(const bf16x8*)&As_hi[ra];
            if (SPLIT) al[i] = *(const bf16x8*)&As_lo[ra];
            const int rb = (wn0 + 16 * i + fm) * LDT + fq * 8;
            bh[i] = *(const bf16x8*)&Bs_hi[rb];
            if (SPLIT) bl[i] = *(const bf16x8*)&Bs_lo[rb];
        }
        #pragma unroll
        for (int i = 0; i < 4; ++i)
            #pragma unroll
            for (int j = 0; j < 4; ++j) {
                acc[i][j] = __builtin_amdgcn_mfma_f32_16x16x32_bf16(ah[i], bh[j], acc[i][j], 0, 0, 0);
                if (SPLIT) {
                    acc[i][j] = __builtin_amdgcn_mfma_f32_16x16x32_bf16(ah[i], bl[j], acc[i][j], 0, 0, 0);
                    acc[i][j] = __builtin_amdgcn_mfma_f32_16x16x32_bf16(al[i], bh[j], acc[i][j], 0, 0, 0);
                }
            }
        __syncthreads();
    }

    // ---- epilogue: C/D layout row=(lane>>4)*4+r, col=lane&15
    const float s = SCALE ? scl[0] : 1.0f;
    #pragma unroll
    for (int i = 0; i < 4; ++i) {
        #pragma unroll
        for (int j = 0; j < 4; ++j) {
            const int n = n0 + wn0 + 16 * j + fm;
            float bv = BIAS ? bias[n] : 0.0f;
            #pragma unroll
            for (int r = 0; r < 4; ++r) {
                const int m = m0 + wm0 + 16 * i + fq * 4 + r;
                float v = acc[i][j][r] + bv;
                if (SCALE) v *= s;
                C[(long)m * N + n] = v;
            }
        }
    }
}

// One block (256 threads) per (b,q) row of 1024 scores.
// Softmax over k < len; masked positions written as 0.
__global__ __launch_bounds__(256) void softmax_kernel(
    float* __restrict__ attn, const int* __restrict__ lens)
{
    const int row = blockIdx.x;          // b*TQ + q
    const int b   = row / TQ;
    const int len = lens[b];             // in [512, 1024]
    float* p = attn + (long)row * TK;

    const int tid  = threadIdx.x;
    const int lane = tid & 63;
    const int wave = tid >> 6;

    float x[4];
    float mx = -INFINITY;
    #pragma unroll
    for (int i = 0; i < 4; ++i) {
        const int k = tid + i * 256;
        x[i] = (k < len) ? p[k] : -INFINITY;
        mx = fmaxf(mx, x[i]);
    }
    #pragma unroll
    for (int off = 32; off; off >>= 1) mx = fmaxf(mx, __shfl_xor(mx, off, 64));

    __shared__ float red[8];
    if (lane == 0) red[wave] = mx;
    __syncthreads();
    mx = fmaxf(fmaxf(red[0], red[1]), fmaxf(red[2], red[3]));

    float e[4];
    float sum = 0.0f;
    #pragma unroll
    for (int i = 0; i < 4; ++i) {
        const int k = tid + i * 256;
        e[i] = (k < len) ? __expf(x[i] - mx) : 0.0f;
        sum += e[i];
    }
    #pragma unroll
    for (int off = 32; off; off >>= 1) sum += __shfl_xor(sum, off, 64);
    if (lane == 0) red[4 + wave] = sum;
    __syncthreads();
    sum = red[4] + red[5] + red[6] + red[7];

    const float inv = 1.0f / sum;
    #pragma unroll
    for (int i = 0; i < 4; ++i) {
        const int k = tid + i * 256;
        p[k] = e[i] * inv;               // masked lanes write exact 0
    }
}

extern "C" void kernel_launch(void* const* d_in, const int* in_sizes, int n_in,
                              void* d_out, int out_size, void* d_ws, size_t ws_size,
                              hipStream_t stream) {
    (void)in_sizes; (void)n_in; (void)out_size; (void)d_ws; (void)ws_size;

    const float* query = (const float*)d_in[0];   // B,TQ,D
    const float* keys  = (const float*)d_in[1];   // B,TK,D
    const int*   lens  = (const int*)d_in[2];     // B
    const float* Wq    = (const float*)d_in[3];   // D,D (row d, col e)
    const float* bq    = (const float*)d_in[4];   // D
    const float* scale = (const float*)d_in[5];   // 1

    float* out  = (float*)d_out;
    float* ctx  = out;                               // B*TQ*D
    float* attn = out + (size_t)BB * TQ * DD;        // B*TQ*TK
    float* aq   = ctx;  // att_query scratch: ctx region is dead until step 4

    // 1) att_query = query @ Wq^T + bq   (split-bf16, M=8192,N=512,K=512)
    mfma_gemm<true, true, true, false>
        <<<dim3(DD / 128, (BB * TQ) / 128, 1), 256, 0, stream>>>(
        query, Wq, aq, bq, nullptr, BB * TQ, DD, DD, 0, 0, 0);

    // 2) scores = att_query @ keys^T * scale (split-bf16, batched) -> attn region
    mfma_gemm<true, true, false, true>
        <<<dim3(TK / 128, TQ / 128, BB), 256, 0, stream>>>(
        aq, keys, attn, nullptr, scale, TQ, TK, DD,
        (long)TQ * DD, (long)TK * DD, (long)TQ * TK);

    // 3) masked softmax in place
    softmax_kernel<<<BB * TQ, 256, 0, stream>>>(attn, lens);

    // 4) context = attn @ keys (plain bf16, batched) -> overwrites aq (dead)
    mfma_gemm<false, false, false, false>
        <<<dim3(DD / 128, TQ / 128, BB), 256, 0, stream>>>(
        attn, keys, ctx, nullptr, nullptr, TQ, DD, TK,
        (long)TQ * TK, (long)TK * DD, (long)TQ * DD);
}

// Round 3
// 197.855 us; speedup vs baseline: 2.6761x; 1.1381x over previous
//
#include <hip/hip_runtime.h>
#include <math.h>

#define BB 16
#define TQ 512
#define TK 1024
#define DD 512

typedef __bf16 bf16x8 __attribute__((ext_vector_type(8)));
typedef __bf16 bf16x4v __attribute__((ext_vector_type(4)));
typedef _Float16 f16x8 __attribute__((ext_vector_type(8)));
typedef _Float16 f16x4v __attribute__((ext_vector_type(4)));
typedef float f32x4 __attribute__((ext_vector_type(4)));

// MFMA GEMM, fp32 in / fp32 out.
//  SPLIT=true : split-bf16 (hi+lo, 3 MFMAs) ~ fp32 accuracy
//  SPLIT=false: plain fp16 (1 MFMA), rel err ~2^-11
//  BT=true : C[m][n] = sum_k A[m][k] * Bm[n][k]
//  BT=false: C[m][n] = sum_k A[m][k] * Bm[k][n]
// Block tile TM x 128 (TM in {64,128}), 256 threads = 4 waves in 2x2,
// wave tile (TM/2) x 64, K-step 32. Requires M%TM==0, N%128==0, K%32==0.
template<int TM, bool SPLIT, bool BT, bool BIAS, bool SCALE>
__global__ __launch_bounds__(256) void mfma_gemm(
    const float* __restrict__ A, const float* __restrict__ Bm,
    float* __restrict__ C, const float* __restrict__ bias,
    const float* __restrict__ scl,
    int N, int K, long sA, long sB, long sC)
{
    constexpr int WI  = TM / 32;   // m-frags per wave
    constexpr int LDT = 40;        // ushorts per 32-k row (8 pad; row*80B is 16B-aligned)
    __shared__ unsigned short As_hi[TM * LDT];
    __shared__ unsigned short Bs_hi[128 * LDT];
    __shared__ unsigned short As_lo[SPLIT ? TM * LDT : 8];
    __shared__ unsigned short Bs_lo[SPLIT ? 128 * LDT : 8];

    const int bz = blockIdx.z;
    A  += (long)bz * sA;
    Bm += (long)bz * sB;
    C  += (long)bz * sC;

    const int m0 = blockIdx.y * TM;
    const int n0 = blockIdx.x * 128;
    const int tid  = threadIdx.x;
    const int lane = tid & 63;
    const int wave = tid >> 6;
    const int wm0 = (wave >> 1) * (TM / 2);
    const int wn0 = (wave & 1) * 64;
    const int fm = lane & 15;
    const int fq = lane >> 4;

    f32x4 acc[WI][4];
    #pragma unroll
    for (int i = 0; i < WI; ++i)
        #pragma unroll
        for (int j = 0; j < 4; ++j) {
            f32x4 z = {0.f, 0.f, 0.f, 0.f};
            acc[i][j] = z;
        }

    for (int k0 = 0; k0 < K; k0 += 32) {
        // ---- stage A tile: TM rows x 32 k (fp32 -> f16 or bf16 hi/lo, native cvt)
        #pragma unroll
        for (int i = 0; i < WI; ++i) {
            const int s   = tid + i * 256;
            const int row = s >> 3;
            const int c4  = (s & 7) << 2;
            const float4 v = *(const float4*)(A + (long)(m0 + row) * K + k0 + c4);
            if (SPLIT) {
                const __bf16 h0 = (__bf16)v.x, h1 = (__bf16)v.y,
                             h2 = (__bf16)v.z, h3 = (__bf16)v.w;
                bf16x4v hv = {h0, h1, h2, h3};
                *(bf16x4v*)&As_hi[row * LDT + c4] = hv;
                bf16x4v lv = {(__bf16)(v.x - (float)h0), (__bf16)(v.y - (float)h1),
                              (__bf16)(v.z - (float)h2), (__bf16)(v.w - (float)h3)};
                *(bf16x4v*)&As_lo[row * LDT + c4] = lv;
            } else {
                f16x4v hv = {(_Float16)v.x, (_Float16)v.y, (_Float16)v.z, (_Float16)v.w};
                *(f16x4v*)&As_hi[row * LDT + c4] = hv;
            }
        }
        // ---- stage B tile into Bs[n][k]
        if (BT) {
            #pragma unroll
            for (int i = 0; i < 4; ++i) {
                const int s   = tid + i * 256;
                const int row = s >> 3;          // n
                const int c4  = (s & 7) << 2;    // k
                const float4 v = *(const float4*)(Bm + (long)(n0 + row) * K + k0 + c4);
                if (SPLIT) {
                    const __bf16 h0 = (__bf16)v.x, h1 = (__bf16)v.y,
                                 h2 = (__bf16)v.z, h3 = (__bf16)v.w;
                    bf16x4v hv = {h0, h1, h2, h3};
                    *(bf16x4v*)&Bs_hi[row * LDT + c4] = hv;
                    bf16x4v lv = {(__bf16)(v.x - (float)h0), (__bf16)(v.y - (float)h1),
                                  (__bf16)(v.z - (float)h2), (__bf16)(v.w - (float)h3)};
                    *(bf16x4v*)&Bs_lo[row * LDT + c4] = lv;
                } else {
                    f16x4v hv = {(_Float16)v.x, (_Float16)v.y, (_Float16)v.z, (_Float16)v.w};
                    *(f16x4v*)&Bs_hi[row * LDT + c4] = hv;
                }
            }
        } else {
            // B is K x N: thread t covers n = t&127, k-half = t>>7 (16 k each).
            const int n  = tid & 127;
            const int kh = tid >> 7;
            const float* src = Bm + (long)(k0 + kh * 16) * N + n0 + n;
            float xs[16];
            #pragma unroll
            for (int j2 = 0; j2 < 16; ++j2) xs[j2] = src[(long)j2 * N];
            #pragma unroll
            for (int w2 = 0; w2 < 4; ++w2) {
                if (SPLIT) {
                    const __bf16 h0 = (__bf16)xs[w2*4+0], h1 = (__bf16)xs[w2*4+1],
                                 h2 = (__bf16)xs[w2*4+2], h3 = (__bf16)xs[w2*4+3];
                    bf16x4v hv = {h0, h1, h2, h3};
                    *(bf16x4v*)&Bs_hi[n * LDT + kh * 16 + w2 * 4] = hv;
                    bf16x4v lv = {(__bf16)(xs[w2*4+0] - (float)h0),
                                  (__bf16)(xs[w2*4+1] - (float)h1),
                                  (__bf16)(xs[w2*4+2] - (float)h2),
                                  (__bf16)(xs[w2*4+3] - (float)h3)};
                    *(bf16x4v*)&Bs_lo[n * LDT + kh * 16 + w2 * 4] = lv;
                } else {
                    f16x4v hv = {(_Float16)xs[w2*4+0], (_Float16)xs[w2*4+1],
                                 (_Float16)xs[w2*4+2], (_Float16)xs[w2*4+3]};
                    *(f16x4v*)&Bs_hi[n * LDT + kh * 16 + w2 * 4] = hv;
                }
            }
        }
        __syncthreads();

        // ---- fragments + MFMA
        if (SPLIT) {
            bf16x8 ah[WI], al[WI], bh[4], bl[4];
            #pragma unroll
            for (int i = 0; i < WI; ++i) {
                const int ra = (wm0 + 16 * i + fm) * LDT + fq * 8;
                ah[i] = *(const bf16x8*)&As_hi[ra];
                al[i] = *(const bf16x8*)&As_lo[ra];
            }
            #pragma unroll
            for (int j = 0; j < 4; ++j) {
                const int rb = (wn0 + 16 * j + fm) * LDT + fq * 8;
                bh[j] = *(const bf16x8*)&Bs_hi[rb];
                bl[j] = *(const bf16x8*)&Bs_lo[rb];
            }
            #pragma unroll
            for (int i = 0; i < WI; ++i)
                #pragma unroll
                for (int j = 0; j < 4; ++j) {
                    acc[i][j] = __builtin_amdgcn_mfma_f32_16x16x32_bf16(ah[i], bh[j], acc[i][j], 0, 0, 0);
                    acc[i][j] = __builtin_amdgcn_mfma_f32_16x16x32_bf16(ah[i], bl[j], acc[i][j], 0, 0, 0);
                    acc[i][j] = __builtin_amdgcn_mfma_f32_16x16x32_bf16(al[i], bh[j], acc[i][j], 0, 0, 0);
                }
        } else {
            f16x8 fa[WI], fb[4];
            #pragma unroll
            for (int i = 0; i < WI; ++i)
                fa[i] = *(const f16x8*)&As_hi[(wm0 + 16 * i + fm) * LDT + fq * 8];
            #pragma unroll
            for (int j = 0; j < 4; ++j)
                fb[j] = *(const f16x8*)&Bs_hi[(wn0 + 16 * j + fm) * LDT + fq * 8];
            #pragma unroll
            for (int i = 0; i < WI; ++i)
                #pragma unroll
                for (int j = 0; j < 4; ++j)
                    acc[i][j] = __builtin_amdgcn_mfma_f32_16x16x32_f16(fa[i], fb[j], acc[i][j], 0, 0, 0);
        }
        __syncthreads();
    }

    // ---- epilogue: C/D layout row=(lane>>4)*4+r, col=lane&15
    const float s = SCALE ? scl[0] : 1.0f;
    #pragma unroll
    for (int i = 0; i < WI; ++i) {
        #pragma unroll
        for (int j = 0; j < 4; ++j) {
            const int n = n0 + wn0 + 16 * j + fm;
            float bv = BIAS ? bias[n] : 0.0f;
            #pragma unroll
            for (int r = 0; r < 4; ++r) {
                const int m = m0 + wm0 + 16 * i + fq * 4 + r;
                float v = acc[i][j][r] + bv;
                if (SCALE) v *= s;
                C[(long)m * N + n] = v;
            }
        }
    }
}

// One block (256 threads) per (b,q) row of 1024 scores; float4 per thread.
// Softmax over k < len; masked positions written as 0.
__global__ __launch_bounds__(256) void softmax_kernel(
    float* __restrict__ attn, const int* __restrict__ lens)
{
    const int row = blockIdx.x;          // b*TQ + q
    const int b   = row >> 9;            // row / TQ (TQ=512)
    const int len = lens[b];
    float* p = attn + (long)row * TK;

    const int tid  = threadIdx.x;
    const int lane = tid & 63;
    const int wave = tid >> 6;
    const int k0   = tid * 4;

    const float4 v = *(const float4*)(p + k0);
    float x[4] = {v.x, v.y, v.z, v.w};
    float mx = -INFINITY;
    #pragma unroll
    for (int i = 0; i < 4; ++i) {
        if (k0 + i < len) mx = fmaxf(mx, x[i]);
        else x[i] = -INFINITY;
    }
    #pragma unroll
    for (int off = 32; off; off >>= 1) mx = fmaxf(mx, __shfl_xor(mx, off, 64));

    __shared__ float red[8];
    if (lane == 0) red[wave] = mx;
    __syncthreads();
    mx = fmaxf(fmaxf(red[0], red[1]), fmaxf(red[2], red[3]));

    float e[4];
    float sum = 0.0f;
    #pragma unroll
    for (int i = 0; i < 4; ++i) {
        e[i] = (x[i] > -INFINITY) ? __expf(x[i] - mx) : 0.0f;
        sum += e[i];
    }
    #pragma unroll
    for (int off = 32; off; off >>= 1) sum += __shfl_xor(sum, off, 64);
    if (lane == 0) red[4 + wave] = sum;
    __syncthreads();
    sum = red[4] + red[5] + red[6] + red[7];

    const float inv = 1.0f / sum;
    float4 o = {e[0] * inv, e[1] * inv, e[2] * inv, e[3] * inv};
    *(float4*)(p + k0) = o;
}

extern "C" void kernel_launch(void* const* d_in, const int* in_sizes, int n_in,
                              void* d_out, int out_size, void* d_ws, size_t ws_size,
                              hipStream_t stream) {
    (void)in_sizes; (void)n_in; (void)out_size; (void)d_ws; (void)ws_size;

    const float* query = (const float*)d_in[0];   // B,TQ,D
    const float* keys  = (const float*)d_in[1];   // B,TK,D
    const int*   lens  = (const int*)d_in[2];     // B
    const float* Wq    = (const float*)d_in[3];   // D,D (row d, col e)
    const float* bq    = (const float*)d_in[4];   // D
    const float* scale = (const float*)d_in[5];   // 1

    float* out  = (float*)d_out;
    float* ctx  = out;                               // B*TQ*D
    float* attn = out + (size_t)BB * TQ * DD;        // B*TQ*TK
    float* aq   = ctx;  // att_query scratch: ctx region is dead until step 4

    // 1) att_query = query @ Wq^T + bq   (fp16, TM=64: 512 blocks)
    mfma_gemm<64, false, true, true, false>
        <<<dim3(DD / 128, (BB * TQ) / 64, 1), 256, 0, stream>>>(
        query, Wq, aq, bq, nullptr, DD, DD, 0, 0, 0);

    // 2) scores = att_query @ keys^T * scale (split-bf16, TM=128: 512 blocks)
    mfma_gemm<128, true, true, false, true>
        <<<dim3(TK / 128, TQ / 128, BB), 256, 0, stream>>>(
        aq, keys, attn, nullptr, scale, TK, DD,
        (long)TQ * DD, (long)TK * DD, (long)TQ * TK);

    // 3) masked softmax in place
    softmax_kernel<<<BB * TQ, 256, 0, stream>>>(attn, lens);

    // 4) context = attn @ keys (fp16, TM=64: 512 blocks)
    mfma_gemm<64, false, false, false, false>
        <<<dim3(DD / 128, TQ / 64, BB), 256, 0, stream>>>(
        attn, keys, ctx, nullptr, nullptr, DD, TK,
        (long)TQ * TK, (long)TK * DD, (long)TQ * DD);
}

// Round 4
// 189.481 us; speedup vs baseline: 2.7944x; 1.0442x over previous
//
#include <hip/hip_runtime.h>
#include <math.h>

#define BB 16
#define TQ 512
#define TK 1024
#define DD 512

typedef __bf16 bf16x8 __attribute__((ext_vector_type(8)));
typedef __bf16 bf16x4v __attribute__((ext_vector_type(4)));
typedef _Float16 f16x8 __attribute__((ext_vector_type(8)));
typedef _Float16 f16x4v __attribute__((ext_vector_type(4)));
typedef float f32x4 __attribute__((ext_vector_type(4)));

__device__ __forceinline__ unsigned short f16b(float x) {
    _Float16 h = (_Float16)x;
    return __builtin_bit_cast(unsigned short, h);
}
__device__ __forceinline__ unsigned short bf16b(float x) {
    __bf16 h = (__bf16)x;
    return __builtin_bit_cast(unsigned short, h);
}

// async global(16B/lane) -> LDS (wave-uniform base + lane*16)
__device__ __forceinline__ void gload16(const void* g, void* l) {
    __builtin_amdgcn_global_load_lds(
        (const __attribute__((address_space(1))) unsigned int*)g,
        (__attribute__((address_space(3))) unsigned int*)l, 16, 0, 0);
}

// ============================================================================
// FAST PATH: NT GEMM on pre-converted 16-bit operands, global_load_lds staging.
//  C[m][n] = sum_k A[m][k]*B[n][k]  (both row-major M|N x K, 16-bit)
//  SPLIT: A=A0+A1, B=B0+B1 bf16 hi/lo, 3 MFMAs (ah*bh + ah*bl + al*bh)
//  !SPLIT: plain fp16 single MFMA.
//  OM=0: C fp32.  OM=1: write bf16 hi->D0, lo->D1 (for aq).
// Tile TM x 128, 256 thr = 4 waves 2x2, wave tile (TM/2)x64, BK=64.
// LDS unpadded; 16B chunks XOR-swizzled within each 128B row:
//   slot = row*8 + (g ^ (row&7)); staging lane fetches the matching global
//   chunk so ds_read_b128 fragments spread across all 32 banks.
// ============================================================================
template<int TM, bool SPLIT, int OM, bool BIAS, bool SCALE>
__global__ __launch_bounds__(256) void gemm16(
    const unsigned short* __restrict__ A0, const unsigned short* __restrict__ A1,
    const unsigned short* __restrict__ B0, const unsigned short* __restrict__ B1,
    float* __restrict__ C, unsigned short* __restrict__ D0,
    unsigned short* __restrict__ D1,
    const float* __restrict__ bias, const float* __restrict__ scl,
    int N, int K, long sA, long sB, long sC)
{
    constexpr int WI = TM / 32;         // m-frags per wave
    constexpr int IA = TM / 32;         // A staging issues per wave
    __shared__ unsigned short As0[TM * 64];
    __shared__ unsigned short Bs0[128 * 64];
    __shared__ unsigned short As1[SPLIT ? TM * 64 : 8];
    __shared__ unsigned short Bs1[SPLIT ? 128 * 64 : 8];

    const int bz = blockIdx.z;
    const long oA = (long)bz * sA, oB = (long)bz * sB;
    const int m0 = blockIdx.y * TM;
    const int n0 = blockIdx.x * 128;
    const int tid = threadIdx.x, lane = tid & 63, wave = tid >> 6;
    const int wm0 = (wave >> 1) * (TM / 2);
    const int wn0 = (wave & 1) * 64;
    const int fm = lane & 15, fq = lane >> 4;

    f32x4 acc[WI][4];
    #pragma unroll
    for (int i = 0; i < WI; ++i)
        #pragma unroll
        for (int j = 0; j < 4; ++j) {
            f32x4 z = {0.f, 0.f, 0.f, 0.f};
            acc[i][j] = z;
        }

    for (int k0 = 0; k0 < K; k0 += 64) {
        // ---- stage A: TM rows x 64 elems (TM*8 chunks of 16B)
        #pragma unroll
        for (int t = 0; t < IA; ++t) {
            const int sb = (wave * IA + t) * 64;       // wave-uniform base slot
            const int slot = sb + lane;
            const int row = slot >> 3;
            const int g = (slot & 7) ^ (row & 7);      // fetch swizzled chunk
            const long ge = oA + (long)(m0 + row) * K + k0 + g * 8;
            gload16(A0 + ge, &As0[sb * 8]);
            if (SPLIT) gload16(A1 + ge, &As1[sb * 8]);
        }
        // ---- stage B: 128 rows x 64 elems
        #pragma unroll
        for (int t = 0; t < 4; ++t) {
            const int sb = (wave * 4 + t) * 64;
            const int slot = sb + lane;
            const int row = slot >> 3;
            const int g = (slot & 7) ^ (row & 7);
            const long ge = oB + (long)(n0 + row) * K + k0 + g * 8;
            gload16(B0 + ge, &Bs0[sb * 8]);
            if (SPLIT) gload16(B1 + ge, &Bs1[sb * 8]);
        }
        __syncthreads();

        #pragma unroll
        for (int s = 0; s < 2; ++s) {
            if (SPLIT) {
                bf16x8 ah[WI], al[WI], bh[4], bl[4];
                #pragma unroll
                for (int i = 0; i < WI; ++i) {
                    const int row = wm0 + 16 * i + fm;
                    const int slot = row * 8 + ((s * 4 + fq) ^ (row & 7));
                    ah[i] = *(const bf16x8*)&As0[slot * 8];
                    al[i] = *(const bf16x8*)&As1[slot * 8];
                }
                #pragma unroll
                for (int j = 0; j < 4; ++j) {
                    const int row = wn0 + 16 * j + fm;
                    const int slot = row * 8 + ((s * 4 + fq) ^ (row & 7));
                    bh[j] = *(const bf16x8*)&Bs0[slot * 8];
                    bl[j] = *(const bf16x8*)&Bs1[slot * 8];
                }
                #pragma unroll
                for (int i = 0; i < WI; ++i)
                    #pragma unroll
                    for (int j = 0; j < 4; ++j) {
                        acc[i][j] = __builtin_amdgcn_mfma_f32_16x16x32_bf16(ah[i], bh[j], acc[i][j], 0, 0, 0);
                        acc[i][j] = __builtin_amdgcn_mfma_f32_16x16x32_bf16(ah[i], bl[j], acc[i][j], 0, 0, 0);
                        acc[i][j] = __builtin_amdgcn_mfma_f32_16x16x32_bf16(al[i], bh[j], acc[i][j], 0, 0, 0);
                    }
            } else {
                f16x8 fa[WI], fb[4];
                #pragma unroll
                for (int i = 0; i < WI; ++i) {
                    const int row = wm0 + 16 * i + fm;
                    const int slot = row * 8 + ((s * 4 + fq) ^ (row & 7));
                    fa[i] = *(const f16x8*)&As0[slot * 8];
                }
                #pragma unroll
                for (int j = 0; j < 4; ++j) {
                    const int row = wn0 + 16 * j + fm;
                    const int slot = row * 8 + ((s * 4 + fq) ^ (row & 7));
                    fb[j] = *(const f16x8*)&Bs0[slot * 8];
                }
                #pragma unroll
                for (int i = 0; i < WI; ++i)
                    #pragma unroll
                    for (int j = 0; j < 4; ++j)
                        acc[i][j] = __builtin_amdgcn_mfma_f32_16x16x32_f16(fa[i], fb[j], acc[i][j], 0, 0, 0);
            }
        }
        __syncthreads();
    }

    // ---- epilogue: C/D layout row=(lane>>4)*4+r, col=lane&15
    const float sv = SCALE ? scl[0] : 1.0f;
    #pragma unroll
    for (int i = 0; i < WI; ++i) {
        #pragma unroll
        for (int j = 0; j < 4; ++j) {
            const int n = n0 + wn0 + 16 * j + fm;
            const float bv = BIAS ? bias[n] : 0.0f;
            #pragma unroll
            for (int r = 0; r < 4; ++r) {
                const int m = m0 + wm0 + 16 * i + fq * 4 + r;
                float v = acc[i][j][r] + bv;
                if (SCALE) v *= sv;
                const long o = (long)bz * sC + (long)m * N + n;
                if (OM == 0) {
                    C[o] = v;
                } else {
                    const __bf16 h = (__bf16)v;
                    D0[o] = __builtin_bit_cast(unsigned short, h);
                    D1[o] = bf16b(v - (float)h);
                }
            }
        }
    }
}

// query + Wq -> fp16 (float4 per thread)
__global__ __launch_bounds__(256) void cvt_qw_kernel(
    const float* __restrict__ q, const float* __restrict__ w,
    unsigned short* __restrict__ q16, unsigned short* __restrict__ w16,
    int nq4, int nw4)
{
    const int t = blockIdx.x * 256 + threadIdx.x;
    const float* s;
    unsigned short* d;
    if (t < nq4)            { s = q + (long)t * 4;         d = q16 + (long)t * 4; }
    else if (t < nq4 + nw4) { s = w + (long)(t - nq4) * 4; d = w16 + (long)(t - nq4) * 4; }
    else return;
    const float4 v = *(const float4*)s;
    f16x4v o = {(_Float16)v.x, (_Float16)v.y, (_Float16)v.z, (_Float16)v.w};
    *(f16x4v*)d = o;
}

// keys -> bf16 hi/lo (same layout) + fp16 transposed [b][d][k], 64x64 tiles
__global__ __launch_bounds__(256) void cvt_keys_kernel(
    const float* __restrict__ keys, unsigned short* __restrict__ kh,
    unsigned short* __restrict__ kl, unsigned short* __restrict__ kT)
{
    __shared__ unsigned short T[64][72];
    const int b = blockIdx.z, kt = blockIdx.x, dt = blockIdx.y;
    const int tid = threadIdx.x;
    const float* src = keys + ((long)b * TK + (long)kt * 64) * DD + dt * 64;

    #pragma unroll
    for (int i = 0; i < 4; ++i) {
        const int slot = tid + i * 256;      // 0..1023
        const int r  = slot >> 4;            // k within tile
        const int c4 = (slot & 15) * 4;      // d within tile
        const float4 v = *(const float4*)(src + (long)r * DD + c4);
        const __bf16 h0 = (__bf16)v.x, h1 = (__bf16)v.y,
                     h2 = (__bf16)v.z, h3 = (__bf16)v.w;
        const long o = ((long)b * TK + kt * 64 + r) * DD + dt * 64 + c4;
        bf16x4v hv = {h0, h1, h2, h3};
        *(bf16x4v*)&kh[o] = hv;
        bf16x4v lv = {(__bf16)(v.x - (float)h0), (__bf16)(v.y - (float)h1),
                      (__bf16)(v.z - (float)h2), (__bf16)(v.w - (float)h3)};
        *(bf16x4v*)&kl[o] = lv;
        T[c4 + 0][r] = f16b(v.x);
        T[c4 + 1][r] = f16b(v.y);
        T[c4 + 2][r] = f16b(v.z);
        T[c4 + 3][r] = f16b(v.w);
    }
    __syncthreads();
    #pragma unroll
    for (int i = 0; i < 4; ++i) {
        const int slot = tid + i * 256;
        const int c  = slot >> 4;            // d within tile
        const int r4 = (slot & 15) * 4;      // k within tile
        const ushort4 o4 = *(const ushort4*)&T[c][r4];
        *(ushort4*)&kT[((long)b * DD + dt * 64 + c) * TK + kt * 64 + r4] = o4;
    }
}

// ============================================================================
// FALLBACK PATH (round-3): fp32-input MFMA GEMM with in-loop conversion.
// ============================================================================
template<int TM, bool SPLIT, bool BT, bool BIAS, bool SCALE>
__global__ __launch_bounds__(256) void mfma_gemm(
    const float* __restrict__ A, const float* __restrict__ Bm,
    float* __restrict__ C, const float* __restrict__ bias,
    const float* __restrict__ scl,
    int N, int K, long sA, long sB, long sC)
{
    constexpr int WI  = TM / 32;
    constexpr int LDT = 40;
    __shared__ unsigned short As_hi[TM * LDT];
    __shared__ unsigned short Bs_hi[128 * LDT];
    __shared__ unsigned short As_lo[SPLIT ? TM * LDT : 8];
    __shared__ unsigned short Bs_lo[SPLIT ? 128 * LDT : 8];

    const int bz = blockIdx.z;
    A  += (long)bz * sA;
    Bm += (long)bz * sB;
    C  += (long)bz * sC;

    const int m0 = blockIdx.y * TM;
    const int n0 = blockIdx.x * 128;
    const int tid  = threadIdx.x;
    const int lane = tid & 63;
    const int wave = tid >> 6;
    const int wm0 = (wave >> 1) * (TM / 2);
    const int wn0 = (wave & 1) * 64;
    const int fm = lane & 15;
    const int fq = lane >> 4;

    f32x4 acc[WI][4];
    #pragma unroll
    for (int i = 0; i < WI; ++i)
        #pragma unroll
        for (int j = 0; j < 4; ++j) {
            f32x4 z = {0.f, 0.f, 0.f, 0.f};
            acc[i][j] = z;
        }

    for (int k0 = 0; k0 < K; k0 += 32) {
        #pragma unroll
        for (int i = 0; i < WI; ++i) {
            const int s   = tid + i * 256;
            const int row = s >> 3;
            const int c4  = (s & 7) << 2;
            const float4 v = *(const float4*)(A + (long)(m0 + row) * K + k0 + c4);
            if (SPLIT) {
                const __bf16 h0 = (__bf16)v.x, h1 = (__bf16)v.y,
                             h2 = (__bf16)v.z, h3 = (__bf16)v.w;
                bf16x4v hv = {h0, h1, h2, h3};
                *(bf16x4v*)&As_hi[row * LDT + c4] = hv;
                bf16x4v lv = {(__bf16)(v.x - (float)h0), (__bf16)(v.y - (float)h1),
                              (__bf16)(v.z - (float)h2), (__bf16)(v.w - (float)h3)};
                *(bf16x4v*)&As_lo[row * LDT + c4] = lv;
            } else {
                f16x4v hv = {(_Float16)v.x, (_Float16)v.y, (_Float16)v.z, (_Float16)v.w};
                *(f16x4v*)&As_hi[row * LDT + c4] = hv;
            }
        }
        if (BT) {
            #pragma unroll
            for (int i = 0; i < 4; ++i) {
                const int s   = tid + i * 256;
                const int row = s >> 3;
                const int c4  = (s & 7) << 2;
                const float4 v = *(const float4*)(Bm + (long)(n0 + row) * K + k0 + c4);
                if (SPLIT) {
                    const __bf16 h0 = (__bf16)v.x, h1 = (__bf16)v.y,
                                 h2 = (__bf16)v.z, h3 = (__bf16)v.w;
                    bf16x4v hv = {h0, h1, h2, h3};
                    *(bf16x4v*)&Bs_hi[row * LDT + c4] = hv;
                    bf16x4v lv = {(__bf16)(v.x - (float)h0), (__bf16)(v.y - (float)h1),
                                  (__bf16)(v.z - (float)h2), (__bf16)(v.w - (float)h3)};
                    *(bf16x4v*)&Bs_lo[row * LDT + c4] = lv;
                } else {
                    f16x4v hv = {(_Float16)v.x, (_Float16)v.y, (_Float16)v.z, (_Float16)v.w};
                    *(f16x4v*)&Bs_hi[row * LDT + c4] = hv;
                }
            }
        } else {
            const int n  = tid & 127;
            const int kh2 = tid >> 7;
            const float* src = Bm + (long)(k0 + kh2 * 16) * N + n0 + n;
            float xs[16];
            #pragma unroll
            for (int j2 = 0; j2 < 16; ++j2) xs[j2] = src[(long)j2 * N];
            #pragma unroll
            for (int w2 = 0; w2 < 4; ++w2) {
                if (SPLIT) {
                    const __bf16 h0 = (__bf16)xs[w2*4+0], h1 = (__bf16)xs[w2*4+1],
                                 h2 = (__bf16)xs[w2*4+2], h3 = (__bf16)xs[w2*4+3];
                    bf16x4v hv = {h0, h1, h2, h3};
                    *(bf16x4v*)&Bs_hi[n * LDT + kh2 * 16 + w2 * 4] = hv;
                    bf16x4v lv = {(__bf16)(xs[w2*4+0] - (float)h0),
                                  (__bf16)(xs[w2*4+1] - (float)h1),
                                  (__bf16)(xs[w2*4+2] - (float)h2),
                                  (__bf16)(xs[w2*4+3] - (float)h3)};
                    *(bf16x4v*)&Bs_lo[n * LDT + kh2 * 16 + w2 * 4] = lv;
                } else {
                    f16x4v hv = {(_Float16)xs[w2*4+0], (_Float16)xs[w2*4+1],
                                 (_Float16)xs[w2*4+2], (_Float16)xs[w2*4+3]};
                    *(f16x4v*)&Bs_hi[n * LDT + kh2 * 16 + w2 * 4] = hv;
                }
            }
        }
        __syncthreads();

        if (SPLIT) {
            bf16x8 ah[WI], al[WI], bh[4], bl[4];
            #pragma unroll
            for (int i = 0; i < WI; ++i) {
                const int ra = (wm0 + 16 * i + fm) * LDT + fq * 8;
                ah[i] = *(const bf16x8*)&As_hi[ra];
                al[i] = *(const bf16x8*)&As_lo[ra];
            }
            #pragma unroll
            for (int j = 0; j < 4; ++j) {
                const int rb = (wn0 + 16 * j + fm) * LDT + fq * 8;
                bh[j] = *(const bf16x8*)&Bs_hi[rb];
                bl[j] = *(const bf16x8*)&Bs_lo[rb];
            }
            #pragma unroll
            for (int i = 0; i < WI; ++i)
                #pragma unroll
                for (int j = 0; j < 4; ++j) {
                    acc[i][j] = __builtin_amdgcn_mfma_f32_16x16x32_bf16(ah[i], bh[j], acc[i][j], 0, 0, 0);
                    acc[i][j] = __builtin_amdgcn_mfma_f32_16x16x32_bf16(ah[i], bl[j], acc[i][j], 0, 0, 0);
                    acc[i][j] = __builtin_amdgcn_mfma_f32_16x16x32_bf16(al[i], bh[j], acc[i][j], 0, 0, 0);
                }
        } else {
            f16x8 fa[WI], fb[4];
            #pragma unroll
            for (int i = 0; i < WI; ++i)
                fa[i] = *(const f16x8*)&As_hi[(wm0 + 16 * i + fm) * LDT + fq * 8];
            #pragma unroll
            for (int j = 0; j < 4; ++j)
                fb[j] = *(const f16x8*)&Bs_hi[(wn0 + 16 * j + fm) * LDT + fq * 8];
            #pragma unroll
            for (int i = 0; i < WI; ++i)
                #pragma unroll
                for (int j = 0; j < 4; ++j)
                    acc[i][j] = __builtin_amdgcn_mfma_f32_16x16x32_f16(fa[i], fb[j], acc[i][j], 0, 0, 0);
        }
        __syncthreads();
    }

    const float s = SCALE ? scl[0] : 1.0f;
    #pragma unroll
    for (int i = 0; i < WI; ++i) {
        #pragma unroll
        for (int j = 0; j < 4; ++j) {
            const int n = n0 + wn0 + 16 * j + fm;
            float bv = BIAS ? bias[n] : 0.0f;
            #pragma unroll
            for (int r = 0; r < 4; ++r) {
                const int m = m0 + wm0 + 16 * i + fq * 4 + r;
                float v = acc[i][j][r] + bv;
                if (SCALE) v *= s;
                C[(long)m * N + n] = v;
            }
        }
    }
}

// Masked softmax, one block per (b,q) row; optional fp16 copy for context A.
__global__ __launch_bounds__(256) void softmax_kernel(
    float* __restrict__ attn, unsigned short* __restrict__ attn16,
    const int* __restrict__ lens)
{
    const int row = blockIdx.x;
    const int b   = row >> 9;            // row / TQ (TQ=512)
    const int len = lens[b];
    float* p = attn + (long)row * TK;

    const int tid  = threadIdx.x;
    const int lane = tid & 63;
    const int wave = tid >> 6;
    const int k0   = tid * 4;

    const float4 v = *(const float4*)(p + k0);
    float x[4] = {v.x, v.y, v.z, v.w};
    float mx = -INFINITY;
    #pragma unroll
    for (int i = 0; i < 4; ++i) {
        if (k0 + i < len) mx = fmaxf(mx, x[i]);
        else x[i] = -INFINITY;
    }
    #pragma unroll
    for (int off = 32; off; off >>= 1) mx = fmaxf(mx, __shfl_xor(mx, off, 64));

    __shared__ float red[8];
    if (lane == 0) red[wave] = mx;
    __syncthreads();
    mx = fmaxf(fmaxf(red[0], red[1]), fmaxf(red[2], red[3]));

    float e[4];
    float sum = 0.0f;
    #pragma unroll
    for (int i = 0; i < 4; ++i) {
        e[i] = (x[i] > -INFINITY) ? __expf(x[i] - mx) : 0.0f;
        sum += e[i];
    }
    #pragma unroll
    for (int off = 32; off; off >>= 1) sum += __shfl_xor(sum, off, 64);
    if (lane == 0) red[4 + wave] = sum;
    __syncthreads();
    sum = red[4] + red[5] + red[6] + red[7];

    const float inv = 1.0f / sum;
    const float o0 = e[0] * inv, o1 = e[1] * inv, o2 = e[2] * inv, o3 = e[3] * inv;
    float4 o = {o0, o1, o2, o3};
    *(float4*)(p + k0) = o;
    if (attn16) {
        f16x4v o16 = {(_Float16)o0, (_Float16)o1, (_Float16)o2, (_Float16)o3};
        *(f16x4v*)&attn16[(long)row * TK + k0] = o16;
    }
}

extern "C" void kernel_launch(void* const* d_in, const int* in_sizes, int n_in,
                              void* d_out, int out_size, void* d_ws, size_t ws_size,
                              hipStream_t stream) {
    (void)in_sizes; (void)n_in; (void)out_size;

    const float* query = (const float*)d_in[0];
    const float* keys  = (const float*)d_in[1];
    const int*   lens  = (const int*)d_in[2];
    const float* Wq    = (const float*)d_in[3];
    const float* bq    = (const float*)d_in[4];
    const float* scale = (const float*)d_in[5];

    float* out  = (float*)d_out;
    float* ctx  = out;                               // B*TQ*D
    float* attn = out + (size_t)BB * TQ * DD;        // B*TQ*TK

    // ws layout (ushort elements)
    const size_t NQ  = (size_t)BB * TQ * DD;   // 4,194,304
    const size_t NW  = (size_t)DD * DD;        //   262,144
    const size_t NK  = (size_t)BB * TK * DD;   // 8,388,608
    const size_t NAT = (size_t)BB * TQ * TK;   // 8,388,608
    const size_t REQ = (NQ + NW + 2 * NQ + 3 * NK + NAT) * 2;  // 92,798,976 B

    if (ws_size >= REQ) {
        unsigned short* w = (unsigned short*)d_ws;
        unsigned short* q16  = w;               w += NQ;
        unsigned short* w16  = w;               w += NW;
        unsigned short* aqh  = w;               w += NQ;
        unsigned short* aql  = w;               w += NQ;
        unsigned short* kh   = w;               w += NK;
        unsigned short* kl   = w;               w += NK;
        unsigned short* kT   = w;               w += NK;
        unsigned short* at16 = w;

        // 0a) query+Wq -> fp16
        const int nq4 = (int)(NQ / 4), nw4 = (int)(NW / 4);
        cvt_qw_kernel<<<(nq4 + nw4 + 255) / 256, 256, 0, stream>>>(
            query, Wq, q16, w16, nq4, nw4);
        // 0b) keys -> bf16 hi/lo + fp16 transposed
        cvt_keys_kernel<<<dim3(TK / 64, DD / 64, BB), 256, 0, stream>>>(
            keys, kh, kl, kT);

        // 1) aq(hi/lo) = f16gemm(query,Wq) + bq   M=8192 N=512 K=512
        gemm16<64, false, 1, true, false>
            <<<dim3(DD / 128, (BB * TQ) / 64, 1), 256, 0, stream>>>(
            q16, nullptr, w16, nullptr, nullptr, aqh, aql, bq, nullptr,
            DD, DD, 0, 0, 0);

        // 2) scores = split-bf16 gemm(aq, keys) * scale  -> attn region (fp32)
        gemm16<128, true, 0, false, true>
            <<<dim3(TK / 128, TQ / 128, BB), 256, 0, stream>>>(
            aqh, aql, kh, kl, attn, nullptr, nullptr, nullptr, scale,
            TK, DD, (long)TQ * DD, (long)TK * DD, (long)TQ * TK);

        // 3) masked softmax in place + fp16 copy
        softmax_kernel<<<BB * TQ, 256, 0, stream>>>(attn, at16, lens);

        // 4) context = f16gemm(attn16, keysT)  M=512 N=512 K=1024 per batch
        gemm16<64, false, 0, false, false>
            <<<dim3(DD / 128, TQ / 64, BB), 256, 0, stream>>>(
            at16, nullptr, kT, nullptr, ctx, nullptr, nullptr, nullptr, nullptr,
            DD, TK, (long)TQ * TK, (long)DD * TK, (long)TQ * DD);
    } else {
        // fallback: round-3 path (in-loop conversion)
        float* aq = ctx;
        mfma_gemm<64, false, true, true, false>
            <<<dim3(DD / 128, (BB * TQ) / 64, 1), 256, 0, stream>>>(
            query, Wq, aq, bq, nullptr, DD, DD, 0, 0, 0);
        mfma_gemm<128, true, true, false, true>
            <<<dim3(TK / 128, TQ / 128, BB), 256, 0, stream>>>(
            aq, keys, attn, nullptr, scale, TK, DD,
            (long)TQ * DD, (long)TK * DD, (long)TQ * TK);
        softmax_kernel<<<BB * TQ, 256, 0, stream>>>(attn, nullptr, lens);
        mfma_gemm<64, false, false, false, false>
            <<<dim3(DD / 128, TQ / 64, BB), 256, 0, stream>>>(
            attn, keys, ctx, nullptr, nullptr, DD, TK,
            (long)TQ * TK, (long)TK * DD, (long)TQ * DD);
    }
}

// Round 5
// 167.782 us; speedup vs baseline: 3.1557x; 1.1293x over previous
//
#include <hip/hip_runtime.h>
#include <math.h>

#define BB 16
#define TQ 512
#define TK 1024
#define DD 512

typedef __bf16 bf16x8 __attribute__((ext_vector_type(8)));
typedef __bf16 bf16x4v __attribute__((ext_vector_type(4)));
typedef _Float16 f16x8 __attribute__((ext_vector_type(8)));
typedef _Float16 f16x4v __attribute__((ext_vector_type(4)));
typedef float f32x4 __attribute__((ext_vector_type(4)));

__device__ __forceinline__ unsigned short f16b(float x) {
    _Float16 h = (_Float16)x;
    return __builtin_bit_cast(unsigned short, h);
}

// async global(16B/lane) -> LDS (wave-uniform base + lane*16)
__device__ __forceinline__ void gload16(const void* g, void* l) {
    __builtin_amdgcn_global_load_lds(
        (const __attribute__((address_space(1))) unsigned int*)g,
        (__attribute__((address_space(3))) unsigned int*)l, 16, 0, 0);
}

// ============================================================================
// FAST PATH: NT GEMM on pre-converted fp16 operands, global_load_lds staging.
//  C[m][n] = sum_k A[m][k]*B[n][k]  (both row-major M|N x K, fp16)
//  OM=0: C fp32.  OM=2: write fp16 -> D0.
// Tile TM x 128, 256 thr = 4 waves 2x2, wave tile (TM/2)x64, BK=64.
// LDS unpadded; 16B chunks XOR-swizzled within each 128B row:
//   slot = row*8 + (g ^ (row&7)); staging lane fetches the matching global
//   chunk so ds_read_b128 fragments spread across all 32 banks.
// ============================================================================
template<int TM, int OM, bool BIAS, bool SCALE>
__global__ __launch_bounds__(256) void gemm16(
    const unsigned short* __restrict__ A0, const unsigned short* __restrict__ B0,
    float* __restrict__ C, unsigned short* __restrict__ D0,
    const float* __restrict__ bias, const float* __restrict__ scl,
    int N, int K, long sA, long sB, long sC)
{
    constexpr int WI = TM / 32;         // m-frags per wave
    constexpr int IA = TM / 32;         // A staging issues per wave
    __shared__ unsigned short As0[TM * 64];
    __shared__ unsigned short Bs0[128 * 64];

    const int bz = blockIdx.z;
    const long oA = (long)bz * sA, oB = (long)bz * sB;
    const int m0 = blockIdx.y * TM;
    const int n0 = blockIdx.x * 128;
    const int tid = threadIdx.x, lane = tid & 63, wave = tid >> 6;
    const int wm0 = (wave >> 1) * (TM / 2);
    const int wn0 = (wave & 1) * 64;
    const int fm = lane & 15, fq = lane >> 4;

    f32x4 acc[WI][4];
    #pragma unroll
    for (int i = 0; i < WI; ++i)
        #pragma unroll
        for (int j = 0; j < 4; ++j) {
            f32x4 z = {0.f, 0.f, 0.f, 0.f};
            acc[i][j] = z;
        }

    for (int k0 = 0; k0 < K; k0 += 64) {
        // ---- stage A: TM rows x 64 elems (TM*8 chunks of 16B)
        #pragma unroll
        for (int t = 0; t < IA; ++t) {
            const int sb = (wave * IA + t) * 64;       // wave-uniform base slot
            const int slot = sb + lane;
            const int row = slot >> 3;
            const int g = (slot & 7) ^ (row & 7);      // fetch swizzled chunk
            gload16(A0 + oA + (long)(m0 + row) * K + k0 + g * 8, &As0[sb * 8]);
        }
        // ---- stage B: 128 rows x 64 elems
        #pragma unroll
        for (int t = 0; t < 4; ++t) {
            const int sb = (wave * 4 + t) * 64;
            const int slot = sb + lane;
            const int row = slot >> 3;
            const int g = (slot & 7) ^ (row & 7);
            gload16(B0 + oB + (long)(n0 + row) * K + k0 + g * 8, &Bs0[sb * 8]);
        }
        __syncthreads();

        #pragma unroll
        for (int s = 0; s < 2; ++s) {
            f16x8 fa[WI], fb[4];
            #pragma unroll
            for (int i = 0; i < WI; ++i) {
                const int row = wm0 + 16 * i + fm;
                const int slot = row * 8 + ((s * 4 + fq) ^ (row & 7));
                fa[i] = *(const f16x8*)&As0[slot * 8];
            }
            #pragma unroll
            for (int j = 0; j < 4; ++j) {
                const int row = wn0 + 16 * j + fm;
                const int slot = row * 8 + ((s * 4 + fq) ^ (row & 7));
                fb[j] = *(const f16x8*)&Bs0[slot * 8];
            }
            #pragma unroll
            for (int i = 0; i < WI; ++i)
                #pragma unroll
                for (int j = 0; j < 4; ++j)
                    acc[i][j] = __builtin_amdgcn_mfma_f32_16x16x32_f16(fa[i], fb[j], acc[i][j], 0, 0, 0);
        }
        __syncthreads();
    }

    // ---- epilogue: C/D layout row=(lane>>4)*4+r, col=lane&15
    const float sv = SCALE ? scl[0] : 1.0f;
    #pragma unroll
    for (int i = 0; i < WI; ++i) {
        #pragma unroll
        for (int j = 0; j < 4; ++j) {
            const int n = n0 + wn0 + 16 * j + fm;
            const float bv = BIAS ? bias[n] : 0.0f;
            #pragma unroll
            for (int r = 0; r < 4; ++r) {
                const int m = m0 + wm0 + 16 * i + fq * 4 + r;
                float v = acc[i][j][r] + bv;
                if (SCALE) v *= sv;
                const long o = (long)bz * sC + (long)m * N + n;
                if (OM == 0) C[o] = v;
                else         D0[o] = f16b(v);
            }
        }
    }
}

// query + Wq -> fp16 (float4 per thread)
__global__ __launch_bounds__(256) void cvt_qw_kernel(
    const float* __restrict__ q, const float* __restrict__ w,
    unsigned short* __restrict__ q16, unsigned short* __restrict__ w16,
    int nq4, int nw4)
{
    const int t = blockIdx.x * 256 + threadIdx.x;
    const float* s;
    unsigned short* d;
    if (t < nq4)            { s = q + (long)t * 4;         d = q16 + (long)t * 4; }
    else if (t < nq4 + nw4) { s = w + (long)(t - nq4) * 4; d = w16 + (long)(t - nq4) * 4; }
    else return;
    const float4 v = *(const float4*)s;
    f16x4v o = {(_Float16)v.x, (_Float16)v.y, (_Float16)v.z, (_Float16)v.w};
    *(f16x4v*)d = o;
}

// keys -> fp16 row-major [b][k][d] + fp16 transposed [b][d][k], 64x64 tiles
__global__ __launch_bounds__(256) void cvt_keys_kernel(
    const float* __restrict__ keys, unsigned short* __restrict__ k16,
    unsigned short* __restrict__ kT)
{
    __shared__ unsigned short T[64][72];
    const int b = blockIdx.z, kt = blockIdx.x, dt = blockIdx.y;
    const int tid = threadIdx.x;
    const float* src = keys + ((long)b * TK + (long)kt * 64) * DD + dt * 64;

    #pragma unroll
    for (int i = 0; i < 4; ++i) {
        const int slot = tid + i * 256;      // 0..1023
        const int r  = slot >> 4;            // k within tile
        const int c4 = (slot & 15) * 4;      // d within tile
        const float4 v = *(const float4*)(src + (long)r * DD + c4);
        const unsigned short h0 = f16b(v.x), h1 = f16b(v.y),
                             h2 = f16b(v.z), h3 = f16b(v.w);
        *(ushort4*)&k16[((long)b * TK + kt * 64 + r) * DD + dt * 64 + c4] =
            make_ushort4(h0, h1, h2, h3);
        T[c4 + 0][r] = h0;
        T[c4 + 1][r] = h1;
        T[c4 + 2][r] = h2;
        T[c4 + 3][r] = h3;
    }
    __syncthreads();
    #pragma unroll
    for (int i = 0; i < 4; ++i) {
        const int slot = tid + i * 256;
        const int c  = slot >> 4;            // d within tile
        const int r4 = (slot & 15) * 4;      // k within tile
        const ushort4 o4 = *(const ushort4*)&T[c][r4];
        *(ushort4*)&kT[((long)b * DD + dt * 64 + c) * TK + kt * 64 + r4] = o4;
    }
}

// ============================================================================
// FALLBACK PATH (round-3): fp32-input MFMA GEMM with in-loop conversion.
// ============================================================================
template<int TM, bool SPLIT, bool BT, bool BIAS, bool SCALE>
__global__ __launch_bounds__(256) void mfma_gemm(
    const float* __restrict__ A, const float* __restrict__ Bm,
    float* __restrict__ C, const float* __restrict__ bias,
    const float* __restrict__ scl,
    int N, int K, long sA, long sB, long sC)
{
    constexpr int WI  = TM / 32;
    constexpr int LDT = 40;
    __shared__ unsigned short As_hi[TM * LDT];
    __shared__ unsigned short Bs_hi[128 * LDT];
    __shared__ unsigned short As_lo[SPLIT ? TM * LDT : 8];
    __shared__ unsigned short Bs_lo[SPLIT ? 128 * LDT : 8];

    const int bz = blockIdx.z;
    A  += (long)bz * sA;
    Bm += (long)bz * sB;
    C  += (long)bz * sC;

    const int m0 = blockIdx.y * TM;
    const int n0 = blockIdx.x * 128;
    const int tid  = threadIdx.x;
    const int lane = tid & 63;
    const int wave = tid >> 6;
    const int wm0 = (wave >> 1) * (TM / 2);
    const int wn0 = (wave & 1) * 64;
    const int fm = lane & 15;
    const int fq = lane >> 4;

    f32x4 acc[WI][4];
    #pragma unroll
    for (int i = 0; i < WI; ++i)
        #pragma unroll
        for (int j = 0; j < 4; ++j) {
            f32x4 z = {0.f, 0.f, 0.f, 0.f};
            acc[i][j] = z;
        }

    for (int k0 = 0; k0 < K; k0 += 32) {
        #pragma unroll
        for (int i = 0; i < WI; ++i) {
            const int s   = tid + i * 256;
            const int row = s >> 3;
            const int c4  = (s & 7) << 2;
            const float4 v = *(const float4*)(A + (long)(m0 + row) * K + k0 + c4);
            if (SPLIT) {
                const __bf16 h0 = (__bf16)v.x, h1 = (__bf16)v.y,
                             h2 = (__bf16)v.z, h3 = (__bf16)v.w;
                bf16x4v hv = {h0, h1, h2, h3};
                *(bf16x4v*)&As_hi[row * LDT + c4] = hv;
                bf16x4v lv = {(__bf16)(v.x - (float)h0), (__bf16)(v.y - (float)h1),
                              (__bf16)(v.z - (float)h2), (__bf16)(v.w - (float)h3)};
                *(bf16x4v*)&As_lo[row * LDT + c4] = lv;
            } else {
                f16x4v hv = {(_Float16)v.x, (_Float16)v.y, (_Float16)v.z, (_Float16)v.w};
                *(f16x4v*)&As_hi[row * LDT + c4] = hv;
            }
        }
        if (BT) {
            #pragma unroll
            for (int i = 0; i < 4; ++i) {
                const int s   = tid + i * 256;
                const int row = s >> 3;
                const int c4  = (s & 7) << 2;
                const float4 v = *(const float4*)(Bm + (long)(n0 + row) * K + k0 + c4);
                if (SPLIT) {
                    const __bf16 h0 = (__bf16)v.x, h1 = (__bf16)v.y,
                                 h2 = (__bf16)v.z, h3 = (__bf16)v.w;
                    bf16x4v hv = {h0, h1, h2, h3};
                    *(bf16x4v*)&Bs_hi[row * LDT + c4] = hv;
                    bf16x4v lv = {(__bf16)(v.x - (float)h0), (__bf16)(v.y - (float)h1),
                                  (__bf16)(v.z - (float)h2), (__bf16)(v.w - (float)h3)};
                    *(bf16x4v*)&Bs_lo[row * LDT + c4] = lv;
                } else {
                    f16x4v hv = {(_Float16)v.x, (_Float16)v.y, (_Float16)v.z, (_Float16)v.w};
                    *(f16x4v*)&Bs_hi[row * LDT + c4] = hv;
                }
            }
        } else {
            const int n  = tid & 127;
            const int kh2 = tid >> 7;
            const float* src = Bm + (long)(k0 + kh2 * 16) * N + n0 + n;
            float xs[16];
            #pragma unroll
            for (int j2 = 0; j2 < 16; ++j2) xs[j2] = src[(long)j2 * N];
            #pragma unroll
            for (int w2 = 0; w2 < 4; ++w2) {
                if (SPLIT) {
                    const __bf16 h0 = (__bf16)xs[w2*4+0], h1 = (__bf16)xs[w2*4+1],
                                 h2 = (__bf16)xs[w2*4+2], h3 = (__bf16)xs[w2*4+3];
                    bf16x4v hv = {h0, h1, h2, h3};
                    *(bf16x4v*)&Bs_hi[n * LDT + kh2 * 16 + w2 * 4] = hv;
                    bf16x4v lv = {(__bf16)(xs[w2*4+0] - (float)h0),
                                  (__bf16)(xs[w2*4+1] - (float)h1),
                                  (__bf16)(xs[w2*4+2] - (float)h2),
                                  (__bf16)(xs[w2*4+3] - (float)h3)};
                    *(bf16x4v*)&Bs_lo[n * LDT + kh2 * 16 + w2 * 4] = lv;
                } else {
                    f16x4v hv = {(_Float16)xs[w2*4+0], (_Float16)xs[w2*4+1],
                                 (_Float16)xs[w2*4+2], (_Float16)xs[w2*4+3]};
                    *(f16x4v*)&Bs_hi[n * LDT + kh2 * 16 + w2 * 4] = hv;
                }
            }
        }
        __syncthreads();

        if (SPLIT) {
            bf16x8 ah[WI], al[WI], bh[4], bl[4];
            #pragma unroll
            for (int i = 0; i < WI; ++i) {
                const int ra = (wm0 + 16 * i + fm) * LDT + fq * 8;
                ah[i] = *(const bf16x8*)&As_hi[ra];
                al[i] = *(const bf16x8*)&As_lo[ra];
            }
            #pragma unroll
            for (int j = 0; j < 4; ++j) {
                const int rb = (wn0 + 16 * j + fm) * LDT + fq * 8;
                bh[j] = *(const bf16x8*)&Bs_hi[rb];
                bl[j] = *(const bf16x8*)&Bs_lo[rb];
            }
            #pragma unroll
            for (int i = 0; i < WI; ++i)
                #pragma unroll
                for (int j = 0; j < 4; ++j) {
                    acc[i][j] = __builtin_amdgcn_mfma_f32_16x16x32_bf16(ah[i], bh[j], acc[i][j], 0, 0, 0);
                    acc[i][j] = __builtin_amdgcn_mfma_f32_16x16x32_bf16(ah[i], bl[j], acc[i][j], 0, 0, 0);
                    acc[i][j] = __builtin_amdgcn_mfma_f32_16x16x32_bf16(al[i], bh[j], acc[i][j], 0, 0, 0);
                }
        } else {
            f16x8 fa[WI], fb[4];
            #pragma unroll
            for (int i = 0; i < WI; ++i)
                fa[i] = *(const f16x8*)&As_hi[(wm0 + 16 * i + fm) * LDT + fq * 8];
            #pragma unroll
            for (int j = 0; j < 4; ++j)
                fb[j] = *(const f16x8*)&Bs_hi[(wn0 + 16 * j + fm) * LDT + fq * 8];
            #pragma unroll
            for (int i = 0; i < WI; ++i)
                #pragma unroll
                for (int j = 0; j < 4; ++j)
                    acc[i][j] = __builtin_amdgcn_mfma_f32_16x16x32_f16(fa[i], fb[j], acc[i][j], 0, 0, 0);
        }
        __syncthreads();
    }

    const float s = SCALE ? scl[0] : 1.0f;
    #pragma unroll
    for (int i = 0; i < WI; ++i) {
        #pragma unroll
        for (int j = 0; j < 4; ++j) {
            const int n = n0 + wn0 + 16 * j + fm;
            float bv = BIAS ? bias[n] : 0.0f;
            #pragma unroll
            for (int r = 0; r < 4; ++r) {
                const int m = m0 + wm0 + 16 * i + fq * 4 + r;
                float v = acc[i][j][r] + bv;
                if (SCALE) v *= s;
                C[(long)m * N + n] = v;
            }
        }
    }
}

// Masked softmax, one block per (b,q) row; optional fp16 copy for context A.
__global__ __launch_bounds__(256) void softmax_kernel(
    float* __restrict__ attn, unsigned short* __restrict__ attn16,
    const int* __restrict__ lens)
{
    const int row = blockIdx.x;
    const int b   = row >> 9;            // row / TQ (TQ=512)
    const int len = lens[b];
    float* p = attn + (long)row * TK;

    const int tid  = threadIdx.x;
    const int lane = tid & 63;
    const int wave = tid >> 6;
    const int k0   = tid * 4;

    const float4 v = *(const float4*)(p + k0);
    float x[4] = {v.x, v.y, v.z, v.w};
    float mx = -INFINITY;
    #pragma unroll
    for (int i = 0; i < 4; ++i) {
        if (k0 + i < len) mx = fmaxf(mx, x[i]);
        else x[i] = -INFINITY;
    }
    #pragma unroll
    for (int off = 32; off; off >>= 1) mx = fmaxf(mx, __shfl_xor(mx, off, 64));

    __shared__ float red[8];
    if (lane == 0) red[wave] = mx;
    __syncthreads();
    mx = fmaxf(fmaxf(red[0], red[1]), fmaxf(red[2], red[3]));

    float e[4];
    float sum = 0.0f;
    #pragma unroll
    for (int i = 0; i < 4; ++i) {
        e[i] = (x[i] > -INFINITY) ? __expf(x[i] - mx) : 0.0f;
        sum += e[i];
    }
    #pragma unroll
    for (int off = 32; off; off >>= 1) sum += __shfl_xor(sum, off, 64);
    if (lane == 0) red[4 + wave] = sum;
    __syncthreads();
    sum = red[4] + red[5] + red[6] + red[7];

    const float inv = 1.0f / sum;
    const float o0 = e[0] * inv, o1 = e[1] * inv, o2 = e[2] * inv, o3 = e[3] * inv;
    float4 o = {o0, o1, o2, o3};
    *(float4*)(p + k0) = o;
    if (attn16) {
        f16x4v o16 = {(_Float16)o0, (_Float16)o1, (_Float16)o2, (_Float16)o3};
        *(f16x4v*)&attn16[(long)row * TK + k0] = o16;
    }
}

extern "C" void kernel_launch(void* const* d_in, const int* in_sizes, int n_in,
                              void* d_out, int out_size, void* d_ws, size_t ws_size,
                              hipStream_t stream) {
    (void)in_sizes; (void)n_in; (void)out_size;

    const float* query = (const float*)d_in[0];
    const float* keys  = (const float*)d_in[1];
    const int*   lens  = (const int*)d_in[2];
    const float* Wq    = (const float*)d_in[3];
    const float* bq    = (const float*)d_in[4];
    const float* scale = (const float*)d_in[5];

    float* out  = (float*)d_out;
    float* ctx  = out;                               // B*TQ*D
    float* attn = out + (size_t)BB * TQ * DD;        // B*TQ*TK

    // ws layout (ushort elements)
    const size_t NQ  = (size_t)BB * TQ * DD;   // 4,194,304
    const size_t NW  = (size_t)DD * DD;        //   262,144
    const size_t NK  = (size_t)BB * TK * DD;   // 8,388,608
    const size_t NAT = (size_t)BB * TQ * TK;   // 8,388,608
    const size_t REQ = (2 * NQ + NW + 2 * NK + NAT) * 2;  // ~67.6 MB

    if (ws_size >= REQ) {
        unsigned short* w = (unsigned short*)d_ws;
        unsigned short* q16  = w;               w += NQ;
        unsigned short* w16  = w;               w += NW;
        unsigned short* aq16 = w;               w += NQ;
        unsigned short* k16  = w;               w += NK;
        unsigned short* kT   = w;               w += NK;
        unsigned short* at16 = w;

        // 0a) query+Wq -> fp16
        const int nq4 = (int)(NQ / 4), nw4 = (int)(NW / 4);
        cvt_qw_kernel<<<(nq4 + nw4 + 255) / 256, 256, 0, stream>>>(
            query, Wq, q16, w16, nq4, nw4);
        // 0b) keys -> fp16 + fp16 transposed
        cvt_keys_kernel<<<dim3(TK / 64, DD / 64, BB), 256, 0, stream>>>(
            keys, k16, kT);

        // 1) aq16 = f16gemm(query,Wq) + bq   M=8192 N=512 K=512
        gemm16<64, 2, true, false>
            <<<dim3(DD / 128, (BB * TQ) / 64, 1), 256, 0, stream>>>(
            q16, w16, nullptr, aq16, bq, nullptr, DD, DD, 0, 0, 0);

        // 2) scores = f16gemm(aq, keys) * scale -> attn region (fp32)
        gemm16<128, 0, false, true>
            <<<dim3(TK / 128, TQ / 128, BB), 256, 0, stream>>>(
            aq16, k16, attn, nullptr, nullptr, scale,
            TK, DD, (long)TQ * DD, (long)TK * DD, (long)TQ * TK);

        // 3) masked softmax in place + fp16 copy
        softmax_kernel<<<BB * TQ, 256, 0, stream>>>(attn, at16, lens);

        // 4) context = f16gemm(attn16, keysT)  M=512 N=512 K=1024 per batch
        gemm16<64, 0, false, false>
            <<<dim3(DD / 128, TQ / 64, BB), 256, 0, stream>>>(
            at16, kT, ctx, nullptr, nullptr, nullptr,
            DD, TK, (long)TQ * TK, (long)DD * TK, (long)TQ * DD);
    } else {
        // fallback: round-3 path (in-loop conversion)
        float* aq = ctx;
        mfma_gemm<64, false, true, true, false>
            <<<dim3(DD / 128, (BB * TQ) / 64, 1), 256, 0, stream>>>(
            query, Wq, aq, bq, nullptr, DD, DD, 0, 0, 0);
        mfma_gemm<128, true, true, false, true>
            <<<dim3(TK / 128, TQ / 128, BB), 256, 0, stream>>>(
            aq, keys, attn, nullptr, scale, TK, DD,
            (long)TQ * DD, (long)TK * DD, (long)TQ * TK);
        softmax_kernel<<<BB * TQ, 256, 0, stream>>>(attn, nullptr, lens);
        mfma_gemm<64, false, false, false, false>
            <<<dim3(DD / 128, TQ / 64, BB), 256, 0, stream>>>(
            attn, keys, ctx, nullptr, nullptr, DD, TK,
            (long)TQ * TK, (long)TK * DD, (long)TQ * DD);
    }
}